// Round 9
// baseline (90.320 us; speedup 1.0000x reference)
//
#include <hip/hip_runtime.h>
#include <cstdint>

// DirectAU loss: align(u,i) + 0.5*(uniform(u) + uniform(i)), T=2, GAMMA=1.
// N=8192 rows, D=64.
// R9: cooperative launch (R8) never launched (unchecked runtime reject; absmax
// = stub signature). Same fusion goal WITHOUT grid.sync: each gram block
// normalizes its own stripes on the fly from raw fp32 inputs (redundant ~33x,
// trivially cheap) -> k1 deleted, no inter-kernel dependency. Alignment is
// computed by the 32 item-diagonal blocks (mapped to by==0 so they dispatch
// first), which already normalize exactly those item rows during staging.
// 2 dispatches total: main (32x33 grid) + tiny final reduce.
//   main: 256x256-tile X@X^T, mfma_f32_16x16x32_bf16; B-stripe staged
//     fp32->normalize->bf16 into fragment-order LDS (conflict-free
//     ds_read_b128, measured 0 conflicts in R6); A-frags normalized in regs.
//     Fused exp2+sum epilogue; per-block partial; no atomics.
//   final: reduce pa[32] + pg[1056] -> d_out[0].
// Harness floor: ws re-poison fill = 268 MB @ ~80% HBM peak (~42us) per timed
// iteration — immovable; sweeps L2/L3 cold every iteration.

#define NROWS 8192
#define DIM 64
#define NT2 32                            // 8192/256 tiles per side
#define NBLK (NT2 * (NT2 + 1))            // 1056

static constexpr float EXP_SCALE = 5.770780163555852f; // 2*T*log2(e) = 4*log2(e)
static constexpr float EPS_F = 1e-8f;

typedef __bf16 bf16x8 __attribute__((ext_vector_type(8)));
typedef float f32x4 __attribute__((ext_vector_type(4)));

__device__ __forceinline__ float rsq_nr(float s) {
    float r = rsqrtf(s);
    return r * (1.5f - 0.5f * s * r * r);   // one Newton step, ~fp32 accurate
}
__device__ __forceinline__ float dot4(float4 a) {
    return a.x * a.x + a.y * a.y + a.z * a.z + a.w * a.w;
}

// grid (32, 33). by==0: ITEM diagonal tile (bi=bj=bx) + alignment for rows
// bx*256..+256 (dispatched first). by>=1: yy=by-1; yy>=bx -> USER tile
// (bi=bx,bj=yy); yy<bx -> ITEM strict-upper tile (bi=yy,bj=bx).
__global__ void __launch_bounds__(512, 8) gram_fused_kernel(
    const float* __restrict__ user, const float* __restrict__ item,
    float* __restrict__ pa,            // 32 alignment partials
    float* __restrict__ pg)            // NBLK gram partials
{
    const int bx = blockIdx.x, by = blockIdx.y;
    const float* __restrict__ Xf;
    int bi, bj;
    bool align_blk = false;
    if (by == 0) { Xf = item; bi = bx; bj = bx; align_blk = true; }
    else {
        const int yy = by - 1;
        if (yy >= bx) { Xf = user; bi = bx; bj = yy; }
        else          { Xf = item; bi = yy; bj = bx; }
    }
    const bool diag = (bi == bj);

    __shared__ unsigned short lds[16384];          // exactly 32 KB
    float* wsum = reinterpret_cast<float*>(lds);   // aliased post-barrier

    const int wave = threadIdx.x >> 6;
    const int lane = threadIdx.x & 63;

    // ---- A fragments: fp32 load -> row-normalize -> bf16 (registers) ----
    // Row sumsq: lane q in {0..3} holds k = q*8.. and q*8+32.. (16 elems);
    // shuffle-xor 16,32 sums over lanes {r16, +16, +32, +48} = full row.
    bf16x8 a[2][2];
    {
        const int r16 = lane & 15, q = lane >> 4;
        const int arow = bi * 256 + wave * 32 + r16;
        #pragma unroll
        for (int rb = 0; rb < 2; ++rb) {
            const float* gp = Xf + (arow + rb * 16) * DIM + q * 8;
            float4 x0 = *reinterpret_cast<const float4*>(gp);
            float4 x1 = *reinterpret_cast<const float4*>(gp + 4);
            float4 y0 = *reinterpret_cast<const float4*>(gp + 32);
            float4 y1 = *reinterpret_cast<const float4*>(gp + 36);
            float ss = dot4(x0) + dot4(x1) + dot4(y0) + dot4(y1);
            ss += __shfl_xor(ss, 16, 64);
            ss += __shfl_xor(ss, 32, 64);
            const float rs = rsq_nr(ss);
            bf16x8 f0, f1;
            f0[0] = (__bf16)(x0.x * rs); f0[1] = (__bf16)(x0.y * rs);
            f0[2] = (__bf16)(x0.z * rs); f0[3] = (__bf16)(x0.w * rs);
            f0[4] = (__bf16)(x1.x * rs); f0[5] = (__bf16)(x1.y * rs);
            f0[6] = (__bf16)(x1.z * rs); f0[7] = (__bf16)(x1.w * rs);
            f1[0] = (__bf16)(y0.x * rs); f1[1] = (__bf16)(y0.y * rs);
            f1[2] = (__bf16)(y0.z * rs); f1[3] = (__bf16)(y0.w * rs);
            f1[4] = (__bf16)(y1.x * rs); f1[5] = (__bf16)(y1.y * rs);
            f1[6] = (__bf16)(y1.z * rs); f1[7] = (__bf16)(y1.w * rs);
            a[rb][0] = f0; a[rb][1] = f1;
        }
    }

    // ---- stage B-stripe: fp32 -> normalize -> bf16 -> fragment-order LDS ----
    // Chunk n = i*512+tid: row r = n>>3 spans 8 aligned lanes (n&7 = tid&7);
    // shuffle-xor 1,2,4 gives row sumsq. Align blocks also load the matching
    // USER chunk and accumulate sum((u_hat - i_hat)^2).
    float asum = 0.0f;
    {
        const int base = bj * 256;
        #pragma unroll
        for (int i = 0; i < 4; ++i) {
            const int n = i * 512 + threadIdx.x;   // 0..2047
            const int r = n >> 3, c = n & 7;
            const float* gp = Xf + (base + r) * DIM + c * 8;
            float4 v0 = *reinterpret_cast<const float4*>(gp);
            float4 v1 = *reinterpret_cast<const float4*>(gp + 4);
            float ss = dot4(v0) + dot4(v1);
            ss += __shfl_xor(ss, 1, 64);
            ss += __shfl_xor(ss, 2, 64);
            ss += __shfl_xor(ss, 4, 64);
            const float rs = rsq_nr(ss);
            bf16x8 f;
            f[0] = (__bf16)(v0.x * rs); f[1] = (__bf16)(v0.y * rs);
            f[2] = (__bf16)(v0.z * rs); f[3] = (__bf16)(v0.w * rs);
            f[4] = (__bf16)(v1.x * rs); f[5] = (__bf16)(v1.y * rs);
            f[6] = (__bf16)(v1.z * rs); f[7] = (__bf16)(v1.w * rs);
            const int di = (r >> 4) * 1024 + c * 128 + (r & 15) * 8;
            *reinterpret_cast<bf16x8*>(&lds[di]) = f;
            if (align_blk) {
                const float* up = user + (base + r) * DIM + c * 8;
                float4 u0 = *reinterpret_cast<const float4*>(up);
                float4 u1 = *reinterpret_cast<const float4*>(up + 4);
                float us = dot4(u0) + dot4(u1);
                us += __shfl_xor(us, 1, 64);
                us += __shfl_xor(us, 2, 64);
                us += __shfl_xor(us, 4, 64);
                const float urs = rsq_nr(us);
                float d;
                d = u0.x * urs - v0.x * rs; asum += d * d;
                d = u0.y * urs - v0.y * rs; asum += d * d;
                d = u0.z * urs - v0.z * rs; asum += d * d;
                d = u0.w * urs - v0.w * rs; asum += d * d;
                d = u1.x * urs - v1.x * rs; asum += d * d;
                d = u1.y * urs - v1.y * rs; asum += d * d;
                d = u1.z * urs - v1.z * rs; asum += d * d;
                d = u1.w * urs - v1.w * rs; asum += d * d;
            }
        }
    }
    __syncthreads();

    // ---- MFMA + exp2 + sum ----
    float l0 = 0.0f, l1 = 0.0f;
    #pragma unroll
    for (int cb = 0; cb < 16; ++cb) {
        bf16x8 b0 = *reinterpret_cast<const bf16x8*>(&lds[cb * 1024 + lane * 8]);
        bf16x8 b1 = *reinterpret_cast<const bf16x8*>(&lds[cb * 1024 + 512 + lane * 8]);
        #pragma unroll
        for (int rb = 0; rb < 2; ++rb) {
            f32x4 c = {0.f, 0.f, 0.f, 0.f};
            c = __builtin_amdgcn_mfma_f32_16x16x32_bf16(a[rb][0], b0, c, 0, 0, 0);
            c = __builtin_amdgcn_mfma_f32_16x16x32_bf16(a[rb][1], b1, c, 0, 0, 0);
            // exp(-T*max(2-2g,0)) = min(exp2(g*S - S), 1); clamp only where
            // g>1 possible (diagonal tiles).
            #pragma unroll
            for (int e = 0; e < 4; ++e) {
                float ex = __builtin_amdgcn_exp2f(fmaf(c[e], EXP_SCALE, -EXP_SCALE));
                if (diag) ex = fminf(ex, 1.0f);
                if (e & 1) l1 += ex; else l0 += ex;
            }
        }
    }

    float local = l0 + l1;
    #pragma unroll
    for (int m = 1; m < 64; m <<= 1) local += __shfl_xor(local, m, 64);
    if (align_blk) {
        #pragma unroll
        for (int m = 1; m < 64; m <<= 1) asum += __shfl_xor(asum, m, 64);
    }
    __syncthreads();                 // all waves done reading lds
    if (lane == 0) { wsum[wave] = local; wsum[8 + wave] = asum; }
    __syncthreads();
    if (threadIdx.x == 0) {
        float t = 0.f, A = 0.f;
        #pragma unroll
        for (int w = 0; w < 8; ++w) { t += wsum[w]; A += wsum[8 + w]; }
        pg[by * NT2 + bx] = diag ? t : 2.0f * t;
        if (align_blk) pa[bx] = A;
    }
}

// ---- final: reduce pa[32] + pg[1056], combine, write scalar ----------------
__global__ void __launch_bounds__(256) final_kernel(
    const float* __restrict__ pa, const float* __restrict__ pg,
    float* __restrict__ out)
{
    float a = 0.f, su = 0.f, si = 0.f;
    if (threadIdx.x < NT2) a = pa[threadIdx.x];
    for (int s = threadIdx.x; s < NBLK; s += 256) {
        const int px = s & (NT2 - 1), py = s >> 5;
        const float v = pg[s];
        // py==0: item diag; else yy=py-1: user iff yy>=px
        if (py != 0 && (py - 1) >= px) su += v; else si += v;
    }
    #pragma unroll
    for (int m = 1; m < 64; m <<= 1) {
        a  += __shfl_xor(a,  m, 64);
        su += __shfl_xor(su, m, 64);
        si += __shfl_xor(si, m, 64);
    }
    __shared__ float r[12];
    const int wave = threadIdx.x >> 6, lane = threadIdx.x & 63;
    if (lane == 0) { r[wave] = a; r[4 + wave] = su; r[8 + wave] = si; }
    __syncthreads();
    if (threadIdx.x == 0) {
        float A  = r[0] + r[1] + r[2]  + r[3];
        float SU = r[4] + r[5] + r[6]  + r[7];
        float SI = r[8] + r[9] + r[10] + r[11];
        const float n = (float)NROWS;
        const float denom = n * (n - 1.0f);
        out[0] = A / n + 0.5f * (logf((SU - n) / denom + EPS_F)
                               + logf((SI - n) / denom + EPS_F));
    }
}

extern "C" void kernel_launch(void* const* d_in, const int* in_sizes, int n_in,
                              void* d_out, int out_size, void* d_ws, size_t ws_size,
                              hipStream_t stream)
{
    const float* user = (const float*)d_in[0];
    const float* item = (const float*)d_in[1];

    float* pa = (float*)d_ws;          // 32 floats
    float* pg = pa + NT2;              // 1056 floats

    gram_fused_kernel<<<dim3(NT2, NT2 + 1), 512, 0, stream>>>(user, item, pa, pg);
    final_kernel<<<1, 256, 0, stream>>>(pa, pg, (float*)d_out);
}

// Round 10
// 88.544 us; speedup vs baseline: 1.0201x; 1.0201x over previous
//
#include <hip/hip_runtime.h>
#include <cstdint>

// DirectAU loss: align(u,i) + 0.5*(uniform(u) + uniform(i)), T=2, GAMMA=1.
// N=8192 rows, D=64.
// R10 = R6 core (best, 83.8us) + two changes:
//  (a) k3 dispatch deleted: gram blocks atomicAdd weighted partials into 32
//      hashed device slots + device counter w/ threadfence release/acquire;
//      last block (old==1055) reduces pa+gsum and writes the scalar.
//  (b) k1 vectorized: float4 loads (16B/lane), 16-lane row groups, ushort4
//      bf16 stores, per-wave partials; k1 also zeroes gsum/ctr every launch
//      (ws re-poisoned 0xAA by harness each iter).
// R9 lesson: on-the-fly fp32 renormalization tripled gram fetch (cold L3 after
// the harness's 268MB poison fill) — bf16 ws round-trip is cheaper. The fill
// (~42us @ 80% HBM peak, in the timed graph) is the immovable floor.

#define NROWS 8192
#define DIM 64
#define NT2 32                            // 8192/256 tiles per side
#define NBLK (NT2 * (NT2 + 1))            // 1056 gram blocks
#define K1_BLOCKS 512                     // 16 rows/block
#define PA_SLOTS (K1_BLOCKS * 4)          // per-wave align partials

static constexpr float EXP_SCALE = 5.770780163555852f; // 2*T*log2(e) = 4*log2(e)
static constexpr float EPS_F = 1e-8f;

typedef __bf16 bf16x8 __attribute__((ext_vector_type(8)));
typedef float f32x4 __attribute__((ext_vector_type(4)));

__device__ __forceinline__ unsigned short f32_to_bf16_rn(float f) {
    union { float f; uint32_t u; } c; c.f = f;
    uint32_t u = c.u;
    uint32_t r = u + 0x7FFFu + ((u >> 16) & 1u);
    return (unsigned short)(r >> 16);
}
__device__ __forceinline__ float rsq_nr(float s) {
    float r = rsqrtf(s);
    return r * (1.5f - 0.5f * s * r * r);
}
__device__ __forceinline__ float dot4(float4 a) {
    return a.x * a.x + a.y * a.y + a.z * a.z + a.w * a.w;
}

// ---- kernel 1: normalize + bf16 cast + per-wave align partial (float4) -----
__global__ void __launch_bounds__(256) normalize_align_kernel(
    const float* __restrict__ user, const float* __restrict__ item,
    unsigned short* __restrict__ xu, unsigned short* __restrict__ xi,
    float* __restrict__ pa, float* __restrict__ gsum)
{
    const int wave = threadIdx.x >> 6;
    const int lane = threadIdx.x & 63;
    const int row  = blockIdx.x * 16 + wave * 4 + (lane >> 4);
    const int col4 = (lane & 15) * 4;
    const int off  = row * DIM + col4;

    float4 u4 = *reinterpret_cast<const float4*>(user + off);
    float4 v4 = *reinterpret_cast<const float4*>(item + off);

    float su = dot4(u4), sv = dot4(v4);
    #pragma unroll
    for (int m = 1; m < 16; m <<= 1) {      // 16-lane row groups
        su += __shfl_xor(su, m, 64);
        sv += __shfl_xor(sv, m, 64);
    }
    const float iu = rsq_nr(su), iv = rsq_nr(sv);

    float un[4] = { u4.x * iu, u4.y * iu, u4.z * iu, u4.w * iu };
    float vn[4] = { v4.x * iv, v4.y * iv, v4.z * iv, v4.w * iv };

    ushort4 ou, oi;
    ou.x = f32_to_bf16_rn(un[0]); ou.y = f32_to_bf16_rn(un[1]);
    ou.z = f32_to_bf16_rn(un[2]); ou.w = f32_to_bf16_rn(un[3]);
    oi.x = f32_to_bf16_rn(vn[0]); oi.y = f32_to_bf16_rn(vn[1]);
    oi.z = f32_to_bf16_rn(vn[2]); oi.w = f32_to_bf16_rn(vn[3]);
    *reinterpret_cast<ushort4*>(xu + off) = ou;
    *reinterpret_cast<ushort4*>(xi + off) = oi;

    float asum = 0.0f;
    #pragma unroll
    for (int e = 0; e < 4; ++e) { float d = un[e] - vn[e]; asum += d * d; }
    #pragma unroll
    for (int m = 1; m < 64; m <<= 1) asum += __shfl_xor(asum, m, 64);
    if (lane == 0) pa[blockIdx.x * 4 + wave] = asum;

    // zero the gram accumulators + counter (ws is 0xAA-poisoned every iter;
    // k1 completes before gram starts, so this is race-free)
    if (blockIdx.x == 0) {
        if (threadIdx.x < 32) gsum[threadIdx.x] = 0.0f;
        if (threadIdx.x == 32) reinterpret_cast<int*>(gsum + 32)[0] = 0;
    }
}

// ---- kernel 2: 256x256 gram tile + exp + device-accumulate + last-block
//      final reduce. Grid (32, 33), R6 decode: by<32 && by>=bx -> USER
//      (bi=bx,bj=by); by<bx -> ITEM strict-upper (bi=by,bj=bx); by==32 ->
//      ITEM diagonal (bi=bj=bx).
// B-stripe fragment-order LDS per 16-row tile: idx = tile*1024 + c*128 +
// r16*8 (c=k/8). ds_read_b128 at tile*1024 + ks*512 + lane*8: conflict-free.
__global__ void __launch_bounds__(512, 8) gram_exp_kernel(
    const unsigned short* __restrict__ xu,
    const unsigned short* __restrict__ xi,
    const float* __restrict__ pa,
    float* __restrict__ gsum,          // [0..15] user, [16..31] item, [32] ctr
    float* __restrict__ out)
{
    const int bx = blockIdx.x, by = blockIdx.y;
    const unsigned short* __restrict__ X;
    int bi, bj;
    if (by < NT2) {
        if (by >= bx) { X = xu; bi = bx; bj = by; }
        else          { X = xi; bi = by; bj = bx; }
    } else            { X = xi; bi = bx; bj = bx; }
    const bool diag = (bi == bj);
    const int  cat  = (by < NT2 && by >= bx) ? 0 : 1;   // 0=user, 1=item

    __shared__ unsigned short lds[16384];          // exactly 32 KB
    float* fsh = reinterpret_cast<float*>(lds);    // aliased post-barrier
    __shared__ int lastflag;

    const int wave = threadIdx.x >> 6;
    const int lane = threadIdx.x & 63;

    // A fragments straight from global (issued early, overlap staging).
    bf16x8 a[2][2];
    {
        const int arow = bi * 256 + wave * 32 + (lane & 15);
        const int acol = (lane >> 4) * 8;
        #pragma unroll
        for (int rb = 0; rb < 2; ++rb)
            #pragma unroll
            for (int ks = 0; ks < 2; ++ks)
                a[rb][ks] = *reinterpret_cast<const bf16x8*>(
                    X + (arow + rb * 16) * DIM + acol + ks * 32);
    }

    // Stage B-stripe (rows bj*256..+256) -> fragment-order LDS.
    {
        const int base = bj * 256;
        #pragma unroll
        for (int i = 0; i < 4; ++i) {
            int n = i * 512 + threadIdx.x;       // 16B-chunk id, 0..2047
            int r = n >> 3, c = n & 7;
            bf16x8 v = *reinterpret_cast<const bf16x8*>(X + (base + r) * DIM + c * 8);
            int di = (r >> 4) * 1024 + c * 128 + (r & 15) * 8;
            *reinterpret_cast<bf16x8*>(&lds[di]) = v;
        }
    }
    __syncthreads();

    float l0 = 0.0f, l1 = 0.0f;
    #pragma unroll
    for (int cb = 0; cb < 16; ++cb) {
        bf16x8 b0 = *reinterpret_cast<const bf16x8*>(&lds[cb * 1024 + lane * 8]);
        bf16x8 b1 = *reinterpret_cast<const bf16x8*>(&lds[cb * 1024 + 512 + lane * 8]);
        #pragma unroll
        for (int rb = 0; rb < 2; ++rb) {
            f32x4 c = {0.f, 0.f, 0.f, 0.f};
            c = __builtin_amdgcn_mfma_f32_16x16x32_bf16(a[rb][0], b0, c, 0, 0, 0);
            c = __builtin_amdgcn_mfma_f32_16x16x32_bf16(a[rb][1], b1, c, 0, 0, 0);
            // exp(-T*max(2-2g,0)) = min(exp2(g*S - S), 1); clamp only where
            // g>1 possible (diagonal tiles).
            #pragma unroll
            for (int e = 0; e < 4; ++e) {
                float ex = __builtin_amdgcn_exp2f(fmaf(c[e], EXP_SCALE, -EXP_SCALE));
                if (diag) ex = fminf(ex, 1.0f);
                if (e & 1) l1 += ex; else l0 += ex;
            }
        }
    }

    float local = l0 + l1;
    #pragma unroll
    for (int m = 1; m < 64; m <<= 1) local += __shfl_xor(local, m, 64);
    __syncthreads();                 // all waves done reading lds
    if (lane == 0) fsh[wave] = local;
    __syncthreads();
    if (threadIdx.x == 0) {
        float t = 0.f;
        #pragma unroll
        for (int w = 0; w < 8; ++w) t += fsh[w];
        if (!diag) t *= 2.0f;
        // device-scope accumulate (hashed slot: ~33 adds/slot, spread in time)
        atomicAdd(&gsum[cat * 16 + (bx & 15)], t);
        __threadfence();             // order value-add before counter-inc
        int old = atomicAdd(reinterpret_cast<int*>(gsum + 32), 1);
        lastflag = (old == NBLK - 1);
    }
    __syncthreads();

    // ---- last block: final reduce + scalar ----
    if (lastflag) {
        __threadfence();             // acquire: see all gsum adds
        float a_ = 0.f;
        for (int s = threadIdx.x; s < PA_SLOTS; s += 512) a_ += pa[s];
        float su_ = 0.f, si_ = 0.f;
        if (threadIdx.x < 16)                         su_ = atomicAdd(&gsum[threadIdx.x], 0.0f);
        else if (threadIdx.x < 32)                    si_ = atomicAdd(&gsum[threadIdx.x], 0.0f);
        #pragma unroll
        for (int m = 1; m < 64; m <<= 1) {
            a_  += __shfl_xor(a_,  m, 64);
            su_ += __shfl_xor(su_, m, 64);
            si_ += __shfl_xor(si_, m, 64);
        }
        __syncthreads();
        if (lane == 0) {
            fsh[wave] = a_; fsh[8 + wave] = su_; fsh[16 + wave] = si_;
        }
        __syncthreads();
        if (threadIdx.x == 0) {
            float A = 0.f, SU = 0.f, SI = 0.f;
            #pragma unroll
            for (int w = 0; w < 8; ++w) {
                A += fsh[w]; SU += fsh[8 + w]; SI += fsh[16 + w];
            }
            const float n = (float)NROWS;
            const float denom = n * (n - 1.0f);
            out[0] = A / n + 0.5f * (logf((SU - n) / denom + EPS_F)
                                   + logf((SI - n) / denom + EPS_F));
        }
    }
}

extern "C" void kernel_launch(void* const* d_in, const int* in_sizes, int n_in,
                              void* d_out, int out_size, void* d_ws, size_t ws_size,
                              hipStream_t stream)
{
    const float* user = (const float*)d_in[0];
    const float* item = (const float*)d_in[1];

    unsigned short* xu = (unsigned short*)d_ws;                 // 1 MB
    unsigned short* xi = xu + (size_t)NROWS * DIM;              // 1 MB
    float* pa   = (float*)(xi + (size_t)NROWS * DIM);           // 2048 floats
    float* gsum = pa + PA_SLOTS;                                // 32 f + 1 int

    normalize_align_kernel<<<K1_BLOCKS, 256, 0, stream>>>(user, item, xu, xi, pa, gsum);
    gram_exp_kernel<<<dim3(NT2, NT2 + 1), 512, 0, stream>>>(xu, xi, pa, gsum, (float*)d_out);
}

// Round 11
// 85.954 us; speedup vs baseline: 1.0508x; 1.0301x over previous
//
#include <hip/hip_runtime.h>
#include <cstdint>

// DirectAU loss: align(u,i) + 0.5*(uniform(u) + uniform(i)), T=2, GAMMA=1.
// N=8192 rows, D=64.
// R11 = R6 skeleton (best, 83.8us; R7/R9/R10 restructurings all lost) with
// ONE change: k1 writes xu/xi in MFMA-FRAGMENT-ORDER global layout
//   Xf[(R>>4)*1024 + (k>>3)*128 + (R&15)*8 + (k&7)]
// so in gram:
//   - A-fragment loads are contiguous 1KB/wave (were 16x 64B scattered rows)
//   - B staging is an identity 32KB contiguous copy (zero swizzle VALU)
//   - MFMA-loop LDS reads unchanged from R6 (measured 0 bank conflicts)
// Dispatch graph: k1 -> gram -> k3 (no atomics/counters — R10's one-cacheline
// counter tail cost +5us). Harness floor: 268MB 0xAA ws re-poison fill
// @ ~80% HBM peak (~42us) per timed iteration, immovable; sweeps caches cold.

#define NROWS 8192
#define DIM 64
#define NT2 32                            // 8192/256 tiles per side
#define GRAM_SLOTS (NT2 * (NT2 + 1))      // 32*33 = 1056
#define K1_BLOCKS 512                     // 16 rows/block, 256 thr
#define PA_SLOTS (K1_BLOCKS * 4)          // per-wave align partials

static constexpr float EXP_SCALE = 5.770780163555852f; // 2*T*log2(e) = 4*log2(e)
static constexpr float EPS_F = 1e-8f;

typedef __bf16 bf16x8 __attribute__((ext_vector_type(8)));
typedef float f32x4 __attribute__((ext_vector_type(4)));

__device__ __forceinline__ unsigned short f32_to_bf16_rn(float f) {
    union { float f; uint32_t u; } c; c.f = f;
    uint32_t u = c.u;
    uint32_t r = u + 0x7FFFu + ((u >> 16) & 1u);
    return (unsigned short)(r >> 16);
}
__device__ __forceinline__ float rsq_nr(float s) {
    float r = rsqrtf(s);
    return r * (1.5f - 0.5f * s * r * r);
}
__device__ __forceinline__ float dot4(float4 a) {
    return a.x * a.x + a.y * a.y + a.z * a.z + a.w * a.w;
}

// ---- kernel 1: normalize + bf16 + fragment-order store + align partial -----
// 256 thr, 16 rows/block. Lane layout: 16-lane row groups (4 rows/wave);
// lane holds cols col4..col4+3 of its row.
__global__ void __launch_bounds__(256) normalize_align_kernel(
    const float* __restrict__ user, const float* __restrict__ item,
    unsigned short* __restrict__ xu, unsigned short* __restrict__ xi,
    float* __restrict__ pa)
{
    const int wave = threadIdx.x >> 6;
    const int lane = threadIdx.x & 63;
    const int row  = blockIdx.x * 16 + wave * 4 + (lane >> 4);
    const int col4 = (lane & 15) * 4;
    const int off  = row * DIM + col4;

    float4 u4 = *reinterpret_cast<const float4*>(user + off);
    float4 v4 = *reinterpret_cast<const float4*>(item + off);

    float su = dot4(u4), sv = dot4(v4);
    #pragma unroll
    for (int m = 1; m < 16; m <<= 1) {      // 16-lane row groups
        su += __shfl_xor(su, m, 64);
        sv += __shfl_xor(sv, m, 64);
    }
    const float iu = rsq_nr(su), iv = rsq_nr(sv);

    float un[4] = { u4.x * iu, u4.y * iu, u4.z * iu, u4.w * iu };
    float vn[4] = { v4.x * iv, v4.y * iv, v4.z * iv, v4.w * iv };

    // fragment-order index: (row>>4)*1024 + (col4>>3)*128 + (row&15)*8 + (col4&7)
    const int fidx = (row >> 4) * 1024 + (col4 >> 3) * 128 + (row & 15) * 8 + (col4 & 7);
    ushort4 ou, oi;
    ou.x = f32_to_bf16_rn(un[0]); ou.y = f32_to_bf16_rn(un[1]);
    ou.z = f32_to_bf16_rn(un[2]); ou.w = f32_to_bf16_rn(un[3]);
    oi.x = f32_to_bf16_rn(vn[0]); oi.y = f32_to_bf16_rn(vn[1]);
    oi.z = f32_to_bf16_rn(vn[2]); oi.w = f32_to_bf16_rn(vn[3]);
    *reinterpret_cast<ushort4*>(xu + fidx) = ou;
    *reinterpret_cast<ushort4*>(xi + fidx) = oi;

    float asum = 0.0f;
    #pragma unroll
    for (int e = 0; e < 4; ++e) { float d = un[e] - vn[e]; asum += d * d; }
    #pragma unroll
    for (int m = 1; m < 64; m <<= 1) asum += __shfl_xor(asum, m, 64);
    if (lane == 0) pa[blockIdx.x * 4 + wave] = asum;
}

// ---- kernel 2: 256x256 gram tile + exp + per-block partial -----------------
// Inputs are fragment-order. Grid (32,33), R6 decode. Per wave:
//   A frag (rb,ks): global byte offset (bi*16+wave*2+rb)*2048 + ks*1024
//                   + lane*16  -> contiguous 1KB/wave.
//   B stage: identity copy of 32KB stripe (Xf elems bj*16384 .. +16384).
//   B frag (cb,ks): lds elem cb*1024 + ks*512 + lane*8 (R6-identical).
__global__ void __launch_bounds__(512, 8) gram_exp_kernel(
    const unsigned short* __restrict__ xu,
    const unsigned short* __restrict__ xi,
    float* __restrict__ pg)
{
    const int bx = blockIdx.x, by = blockIdx.y;
    const unsigned short* __restrict__ X;
    int bi, bj;
    if (by < NT2) {
        if (by >= bx) { X = xu; bi = bx; bj = by; }
        else          { X = xi; bi = by; bj = bx; }
    } else            { X = xi; bi = bx; bj = bx; }
    const bool diag = (bi == bj);

    __shared__ unsigned short lds[16384];          // exactly 32 KB
    float* fsh = reinterpret_cast<float*>(lds);    // aliased post-barrier

    const int wave = threadIdx.x >> 6;
    const int lane = threadIdx.x & 63;

    // A fragments: contiguous 1KB/wave loads (issued first, overlap staging)
    bf16x8 a[2][2];
    {
        const unsigned short* ab = X + (bi * 16 + wave * 2) * 1024 + lane * 8;
        #pragma unroll
        for (int rb = 0; rb < 2; ++rb)
            #pragma unroll
            for (int ks = 0; ks < 2; ++ks)
                a[rb][ks] = *reinterpret_cast<const bf16x8*>(ab + rb * 1024 + ks * 512);
    }

    // B staging: identity 32KB contiguous copy -> LDS
    {
        const unsigned short* sb = X + bj * 16384;
        #pragma unroll
        for (int i = 0; i < 4; ++i) {
            const int n = i * 512 + threadIdx.x;   // 16B-chunk id, 0..2047
            *reinterpret_cast<bf16x8*>(&lds[n * 8]) =
                *reinterpret_cast<const bf16x8*>(sb + n * 8);
        }
    }
    __syncthreads();

    float l0 = 0.0f, l1 = 0.0f;
    #pragma unroll
    for (int cb = 0; cb < 16; ++cb) {
        bf16x8 b0 = *reinterpret_cast<const bf16x8*>(&lds[cb * 1024 + lane * 8]);
        bf16x8 b1 = *reinterpret_cast<const bf16x8*>(&lds[cb * 1024 + 512 + lane * 8]);
        #pragma unroll
        for (int rb = 0; rb < 2; ++rb) {
            f32x4 c = {0.f, 0.f, 0.f, 0.f};
            c = __builtin_amdgcn_mfma_f32_16x16x32_bf16(a[rb][0], b0, c, 0, 0, 0);
            c = __builtin_amdgcn_mfma_f32_16x16x32_bf16(a[rb][1], b1, c, 0, 0, 0);
            // exp(-T*max(2-2g,0)) = min(exp2(g*S - S), 1); clamp only where
            // g>1 possible (diagonal tiles).
            #pragma unroll
            for (int e = 0; e < 4; ++e) {
                float ex = __builtin_amdgcn_exp2f(fmaf(c[e], EXP_SCALE, -EXP_SCALE));
                if (diag) ex = fminf(ex, 1.0f);
                if (e & 1) l1 += ex; else l0 += ex;
            }
        }
    }

    float local = l0 + l1;
    #pragma unroll
    for (int m = 1; m < 64; m <<= 1) local += __shfl_xor(local, m, 64);
    __syncthreads();                 // all waves done reading lds
    if (lane == 0) fsh[wave] = local;
    __syncthreads();
    if (threadIdx.x == 0) {
        float t = 0.f;
        #pragma unroll
        for (int w = 0; w < 8; ++w) t += fsh[w];
        pg[by * NT2 + bx] = diag ? t : 2.0f * t;
    }
}

// ---- kernel 3: reduce partials + combine -----------------------------------
__global__ void __launch_bounds__(256) final_kernel(
    const float* __restrict__ pa, const float* __restrict__ pg,
    float* __restrict__ out)
{
    float a = 0.f, su = 0.f, si = 0.f;
    for (int s = threadIdx.x; s < PA_SLOTS; s += 256) a += pa[s];
    for (int s = threadIdx.x; s < GRAM_SLOTS; s += 256) {
        const int px = s & (NT2 - 1), py = s >> 5;
        const bool is_item = (py == NT2) || (py < px);
        const float v = pg[s];
        if (is_item) si += v; else su += v;
    }
    #pragma unroll
    for (int m = 1; m < 64; m <<= 1) {
        a  += __shfl_xor(a,  m, 64);
        su += __shfl_xor(su, m, 64);
        si += __shfl_xor(si, m, 64);
    }
    __shared__ float r[12];
    const int wave = threadIdx.x >> 6, lane = threadIdx.x & 63;
    if (lane == 0) { r[wave] = a; r[4 + wave] = su; r[8 + wave] = si; }
    __syncthreads();
    if (threadIdx.x == 0) {
        float A  = r[0] + r[1] + r[2]  + r[3];
        float SU = r[4] + r[5] + r[6]  + r[7];
        float SI = r[8] + r[9] + r[10] + r[11];
        const float n = (float)NROWS;
        const float denom = n * (n - 1.0f);
        out[0] = A / n + 0.5f * (logf((SU - n) / denom + EPS_F)
                               + logf((SI - n) / denom + EPS_F));
    }
}

extern "C" void kernel_launch(void* const* d_in, const int* in_sizes, int n_in,
                              void* d_out, int out_size, void* d_ws, size_t ws_size,
                              hipStream_t stream)
{
    const float* user = (const float*)d_in[0];
    const float* item = (const float*)d_in[1];

    unsigned short* xu = (unsigned short*)d_ws;                 // 1 MB
    unsigned short* xi = xu + (size_t)NROWS * DIM;              // 1 MB
    float* pa = (float*)(xi + (size_t)NROWS * DIM);             // 2048 floats
    float* pg = pa + PA_SLOTS;                                  // 1056 floats

    normalize_align_kernel<<<K1_BLOCKS, 256, 0, stream>>>(user, item, xu, xi, pa);
    gram_exp_kernel<<<dim3(NT2, NT2 + 1), 512, 0, stream>>>(xu, xi, pg);
    final_kernel<<<1, 256, 0, stream>>>(pa, pg, (float*)d_out);
}